// Round 5
// baseline (887.052 us; speedup 1.0000x reference)
//
#include <hip/hip_runtime.h>

#define N_NODES 100000
#define N_EDGES 1600000
#define IN_F    128
#define NEG_SLOPE 0.2f
#define NBUCK   512                 // scan width; active buckets = 391
#define PCHUNK  4096                // edges per partition block

__device__ __forceinline__ float bf2f(unsigned short u) {
    return __uint_as_float(((unsigned int)u) << 16);
}

// f32 -> bf16 round-to-nearest-even
__device__ __forceinline__ unsigned short f2bf(float f) {
    unsigned int u = __float_as_uint(f);
    u += 0x7FFFu + ((u >> 16) & 1u);
    return (unsigned short)(u >> 16);
}

// ---------------------------------------------------------------------------
// Fused GEMM hidden layers: featb(bf16) = A @ W (128x128), el/er in epilogue.
// k-loop unrolled x4: ds_read_b128 for A-tile, 4 float4 W rows per step.
// ---------------------------------------------------------------------------
__global__ __launch_bounds__(256) void gemm128_fused(const float* __restrict__ A,
                                                     const float* __restrict__ W,
                                                     const float* __restrict__ al,
                                                     const float* __restrict__ ar,
                                                     unsigned short* __restrict__ featb,
                                                     float* __restrict__ el,
                                                     float* __restrict__ er,
                                                     int nrows) {
    __shared__ float sH[64][IN_F];
    const int t    = threadIdx.x;
    const int row0 = blockIdx.x * 64;

#pragma unroll
    for (int i = 0; i < 8; ++i) {
        int e4 = i * 256 + t;
        int r  = (e4 * 4) >> 7;
        int c  = (e4 * 4) & 127;
        float4 v = make_float4(0.f, 0.f, 0.f, 0.f);
        int gr = row0 + r;
        if (gr < nrows) v = *(const float4*)(A + (size_t)gr * IN_F + c);
        *(float4*)(&sH[r][c]) = v;
    }
    __syncthreads();

    const int tx  = t & 31;
    const int ty  = t >> 5;
    const int col = tx * 4;

    float4 acc[8];
#pragma unroll
    for (int i = 0; i < 8; ++i) acc[i] = make_float4(0.f, 0.f, 0.f, 0.f);

    for (int k = 0; k < IN_F; k += 4) {
        float4 b0 = *(const float4*)(W + (k + 0) * 128 + col);
        float4 b1 = *(const float4*)(W + (k + 1) * 128 + col);
        float4 b2 = *(const float4*)(W + (k + 2) * 128 + col);
        float4 b3 = *(const float4*)(W + (k + 3) * 128 + col);
#pragma unroll
        for (int i = 0; i < 8; ++i) {
            float4 a = *(const float4*)(&sH[ty * 8 + i][k]);
            acc[i].x += a.x * b0.x + a.y * b1.x + a.z * b2.x + a.w * b3.x;
            acc[i].y += a.x * b0.y + a.y * b1.y + a.z * b2.y + a.w * b3.y;
            acc[i].z += a.x * b0.z + a.y * b1.z + a.z * b2.z + a.w * b3.z;
            acc[i].w += a.x * b0.w + a.y * b1.w + a.z * b2.w + a.w * b3.w;
        }
    }

    const float4 alv = *(const float4*)(al + col);
    const float4 arv = *(const float4*)(ar + col);
    const int h = tx >> 3;

#pragma unroll
    for (int i = 0; i < 8; ++i) {
        int r = row0 + ty * 8 + i;
        float4 a = acc[i];
        if (r < nrows) {
            ushort4 u;
            u.x = f2bf(a.x); u.y = f2bf(a.y); u.z = f2bf(a.z); u.w = f2bf(a.w);
            *(ushort4*)(featb + (size_t)r * 128 + col) = u;
        }
        float pel = a.x * alv.x + a.y * alv.y + a.z * alv.z + a.w * alv.w;
        float per = a.x * arv.x + a.y * arv.y + a.z * arv.z + a.w * arv.w;
        pel += __shfl_down(pel, 4); per += __shfl_down(per, 4);
        pel += __shfl_down(pel, 2); per += __shfl_down(per, 2);
        pel += __shfl_down(pel, 1); per += __shfl_down(per, 1);
        if ((tx & 7) == 0 && r < nrows) {
            el[r * 4 + h] = pel;
            er[r * 4 + h] = per;
        }
    }
}

// ---------------------------------------------------------------------------
// Dual GEMM layer 2: feat2b(bf16) = A @ W2, res2(f32) = A @ resW2, el/er fused.
// ---------------------------------------------------------------------------
__global__ __launch_bounds__(256) void gemm16_dual(const float* __restrict__ A,
                                                   const float* __restrict__ W2,
                                                   const float* __restrict__ resW2,
                                                   const float* __restrict__ al,
                                                   const float* __restrict__ ar,
                                                   unsigned short* __restrict__ feat2b,
                                                   float* __restrict__ res2,
                                                   float* __restrict__ el,
                                                   float* __restrict__ er,
                                                   int nrows) {
    __shared__ float sH[64][IN_F];
    const int t    = threadIdx.x;
    const int row0 = blockIdx.x * 64;

#pragma unroll
    for (int i = 0; i < 8; ++i) {
        int e4 = i * 256 + t;
        int r  = (e4 * 4) >> 7;
        int c  = (e4 * 4) & 127;
        float4 v = make_float4(0.f, 0.f, 0.f, 0.f);
        int gr = row0 + r;
        if (gr < nrows) v = *(const float4*)(A + (size_t)gr * IN_F + c);
        *(float4*)(&sH[r][c]) = v;
    }
    __syncthreads();

    const int tx   = t & 7;
    const int ty   = t >> 3;
    const bool isW = tx < 4;
    const int col  = (isW ? tx : tx - 4) * 4;
    const float* Wp = isW ? W2 : resW2;

    float4 acc[2];
    acc[0] = make_float4(0.f, 0.f, 0.f, 0.f);
    acc[1] = make_float4(0.f, 0.f, 0.f, 0.f);

    for (int k = 0; k < IN_F; k += 4) {
        float4 b0 = *(const float4*)(Wp + (k + 0) * 16 + col);
        float4 b1 = *(const float4*)(Wp + (k + 1) * 16 + col);
        float4 b2 = *(const float4*)(Wp + (k + 2) * 16 + col);
        float4 b3 = *(const float4*)(Wp + (k + 3) * 16 + col);
#pragma unroll
        for (int i = 0; i < 2; ++i) {
            float4 a = *(const float4*)(&sH[ty * 2 + i][k]);
            acc[i].x += a.x * b0.x + a.y * b1.x + a.z * b2.x + a.w * b3.x;
            acc[i].y += a.x * b0.y + a.y * b1.y + a.z * b2.y + a.w * b3.y;
            acc[i].z += a.x * b0.z + a.y * b1.z + a.z * b2.z + a.w * b3.z;
            acc[i].w += a.x * b0.w + a.y * b1.w + a.z * b2.w + a.w * b3.w;
        }
    }

    const float4 alv = isW ? *(const float4*)(al + col) : make_float4(0, 0, 0, 0);
    const float4 arv = isW ? *(const float4*)(ar + col) : make_float4(0, 0, 0, 0);

#pragma unroll
    for (int i = 0; i < 2; ++i) {
        int r = row0 + ty * 2 + i;
        float4 a = acc[i];
        if (isW) {
            if (r < nrows) {
                ushort4 u;
                u.x = f2bf(a.x); u.y = f2bf(a.y); u.z = f2bf(a.z); u.w = f2bf(a.w);
                *(ushort4*)(feat2b + (size_t)r * 16 + col) = u;
            }
            float pel = a.x * alv.x + a.y * alv.y + a.z * alv.z + a.w * alv.w;
            float per = a.x * arv.x + a.y * arv.y + a.z * arv.z + a.w * arv.w;
            pel += __shfl_down(pel, 2); per += __shfl_down(per, 2);
            pel += __shfl_down(pel, 1); per += __shfl_down(per, 1);
            if (tx == 0 && r < nrows) { el[r] = pel; er[r] = per; }
        } else if (r < nrows) {
            *(float4*)(res2 + (size_t)r * 16 + col) = a;
        }
    }
}

// ---------------------------------------------------------------------------
// CSR build, locality-aware. Bucket = dst>>8 (256-node windows, 391 active).
// ---------------------------------------------------------------------------
__global__ __launch_bounds__(256) void bucket_count_k(const int* __restrict__ dst,
                                                      int* __restrict__ bcount, int nE) {
    __shared__ int hist[NBUCK];
    const int t = threadIdx.x;
    hist[t] = 0; hist[t + 256] = 0;
    __syncthreads();
    const int start = blockIdx.x * PCHUNK;
#pragma unroll
    for (int j = 0; j < PCHUNK / 256; ++j) {
        int e = start + j * 256 + t;
        if (e < nE) atomicAdd(&hist[dst[e] >> 8], 1);
    }
    __syncthreads();
    if (hist[t])       atomicAdd(&bcount[t],       hist[t]);
    if (hist[t + 256]) atomicAdd(&bcount[t + 256], hist[t + 256]);
}

// exclusive scan of bucket counts -> base; cursor initialized to base
__global__ __launch_bounds__(NBUCK) void scan512(const int* __restrict__ bcount,
                                                 int* __restrict__ bbase,
                                                 int* __restrict__ bcursor) {
    __shared__ int s[NBUCK];
    const int t = threadIdx.x;
    int v = bcount[t];
    s[t] = v;
    __syncthreads();
#pragma unroll
    for (int off = 1; off < NBUCK; off <<= 1) {
        int x = (t >= off) ? s[t - off] : 0;
        __syncthreads();
        s[t] += x;
        __syncthreads();
    }
    int excl = s[t] - v;
    bbase[t]   = excl;
    bcursor[t] = excl;
}

// Counting-sort PCHUNK edges by bucket in LDS, flush coalesced runs.
__global__ __launch_bounds__(512) void partition_k(const int* __restrict__ src,
                                                   const int* __restrict__ dst,
                                                   int* __restrict__ bcursor,
                                                   uint2* __restrict__ pe, int nE) {
    __shared__ int   hist[NBUCK];
    __shared__ int   lstart[NBUCK];
    __shared__ int   gbase[NBUCK];
    __shared__ int   curB[NBUCK];
    __shared__ uint2 reorder[PCHUNK];

    const int t = threadIdx.x;
    const int start = blockIdx.x * PCHUNK;
    const int m = min(PCHUNK, nE - start);

    hist[t] = 0;
    __syncthreads();

    // pass A: histogram
#pragma unroll
    for (int j = 0; j < PCHUNK / 512; ++j) {
        int e = start + j * 512 + t;
        if (e < nE) atomicAdd(&hist[dst[e] >> 8], 1);
    }
    __syncthreads();
    const int cnt = hist[t];

    // scan -> local start
    __shared__ int s[NBUCK];
    s[t] = cnt;
    __syncthreads();
#pragma unroll
    for (int off = 1; off < NBUCK; off <<= 1) {
        int x = (t >= off) ? s[t - off] : 0;
        __syncthreads();
        s[t] += x;
        __syncthreads();
    }
    lstart[t] = s[t] - cnt;
    curB[t]   = s[t] - cnt;
    // reserve global run for this block's share of bucket t
    gbase[t] = cnt ? atomicAdd(&bcursor[t], cnt) : 0;
    __syncthreads();

    // pass B: place into LDS grouped by bucket
#pragma unroll
    for (int j = 0; j < PCHUNK / 512; ++j) {
        int e = start + j * 512 + t;
        if (e < nE) {
            int d = dst[e];
            int pos = atomicAdd(&curB[d >> 8], 1);
            reorder[pos] = make_uint2((unsigned)src[e], (unsigned)d);
        }
    }
    __syncthreads();

    // flush: consecutive LDS slots -> consecutive global slots within runs
    for (int i = t; i < m; i += 512) {
        uint2 ed = reorder[i];
        int b = (int)(ed.y >> 8);
        pe[gbase[b] + (i - lstart[b])] = ed;
    }
}

// One block per bucket: local degree histogram + scan -> rowptr/deg/sorted_src
__global__ __launch_bounds__(256) void bucket_finalize(const uint2* __restrict__ pe,
                                                       const int* __restrict__ bbase,
                                                       int* __restrict__ rowptr,
                                                       int* __restrict__ deg,
                                                       int* __restrict__ sorted_src,
                                                       int nE) {
    __shared__ int deg_l[256];
    __shared__ int s[256];
    __shared__ int cur[256];

    const int b  = blockIdx.x;
    const int t  = threadIdx.x;
    const int base = bbase[b];
    const int endE = (b + 1 < NBUCK) ? bbase[b + 1] : nE;
    const int cnt  = endE - base;
    const int n    = b * 256 + t;

    deg_l[t] = 0;
    __syncthreads();
    for (int i = t; i < cnt; i += 256)
        atomicAdd(&deg_l[pe[base + i].y & 255u], 1);
    __syncthreads();

    const int dv = deg_l[t];
    s[t] = dv;
    __syncthreads();
#pragma unroll
    for (int off = 1; off < 256; off <<= 1) {
        int x = (t >= off) ? s[t - off] : 0;
        __syncthreads();
        s[t] += x;
        __syncthreads();
    }
    const int off_l = s[t] - dv;
    if (n < N_NODES) {
        rowptr[n] = base + off_l;
        deg[n]    = dv;
    }
    cur[t] = off_l;
    __syncthreads();

    for (int i = t; i < cnt; i += 256) {
        uint2 ed = pe[base + i];
        int pos = atomicAdd(&cur[ed.y & 255u], 1);
        sorted_src[base + pos] = (int)ed.x;
    }
}

// ---------------------------------------------------------------------------
// Pull aggregation, H=4, D=32 (128 feats), bf16 gathers, wave per node.
// ---------------------------------------------------------------------------
__global__ __launch_bounds__(256) void gat_agg128(const int* __restrict__ rowptr,
                                                  const int* __restrict__ deg,
                                                  const int* __restrict__ sorted_src,
                                                  const float* __restrict__ el,
                                                  const float* __restrict__ er,
                                                  const unsigned short* __restrict__ featb,
                                                  const float* __restrict__ res,
                                                  float* __restrict__ out) {
    __shared__ int   sS[4][64];
    __shared__ float sW[4][64][4];

    const int wv   = threadIdx.x >> 6;
    const int lane = threadIdx.x & 63;
    const int nd   = blockIdx.x * 4 + wv;

    const int dg = deg[nd];
    const int r0 = rowptr[nd];
    const int h  = lane >> 4;
    const float4 er4 = *(const float4*)(er + nd * 4);

    float den = 0.f;
    float ax = 0.f, ay = 0.f;

    for (int base = 0; base < dg; base += 64) {
        int m = dg - base; if (m > 64) m = 64;
        if (lane < m) {
            int s = sorted_src[r0 + base + lane];
            sS[wv][lane] = s;
            float4 e4 = *(const float4*)(el + s * 4);
            float4 w;
            float v;
            v = e4.x + er4.x; v = v > 0.f ? v : NEG_SLOPE * v; w.x = __expf(v);
            v = e4.y + er4.y; v = v > 0.f ? v : NEG_SLOPE * v; w.y = __expf(v);
            v = e4.z + er4.z; v = v > 0.f ? v : NEG_SLOPE * v; w.z = __expf(v);
            v = e4.w + er4.w; v = v > 0.f ? v : NEG_SLOPE * v; w.w = __expf(v);
            *(float4*)(&sW[wv][lane][0]) = w;
        }
        for (int i = 0; i < m; ++i) {
            int s   = sS[wv][i];
            float w = sW[wv][i][h];
            den += w;
            ushort2 u = *(const ushort2*)(featb + (size_t)s * 128 + lane * 2);
            ax += w * bf2f(u.x);
            ay += w * bf2f(u.y);
        }
    }

    float scale = den > 0.f ? 1.f / den : 0.f;
    float ox = ax * scale, oy = ay * scale;
    size_t o0 = (size_t)nd * 128 + lane * 2;
    if (res) { ox += res[o0]; oy += res[o0 + 1]; }
    ox = fmaxf(ox, 0.f);
    oy = fmaxf(oy, 0.f);
    *(float2*)(out + o0) = make_float2(ox, oy);
}

// ---------------------------------------------------------------------------
// Pull aggregation, H=1, C=16, bf16 gathers, wave per node, shuffle staging.
// ---------------------------------------------------------------------------
__global__ __launch_bounds__(256) void gat_agg16(const int* __restrict__ rowptr,
                                                 const int* __restrict__ deg,
                                                 const int* __restrict__ sorted_src,
                                                 const float* __restrict__ el,
                                                 const float* __restrict__ er,
                                                 const unsigned short* __restrict__ feat2b,
                                                 const float* __restrict__ res,
                                                 float* __restrict__ out, int n) {
    const int t    = threadIdx.x;
    const int nd   = blockIdx.x * 4 + (t >> 6);
    const int lane = t & 63;
    if (nd >= n) return;

    const int f = lane & 15;
    const int q = lane >> 4;
    const int dg = deg[nd];
    const int r0 = rowptr[nd];
    const float erd = er[nd];

    float acc = 0.f, den = 0.f;

    for (int base = 0; base < dg; base += 64) {
        int m = dg - base; if (m > 64) m = 64;
        int s = 0; float w = 0.f;
        if (lane < m) {
            s = sorted_src[r0 + base + lane];
            float v = el[s] + erd;
            v = v > 0.f ? v : NEG_SLOPE * v;
            w = __expf(v);
        }
        den += w;
#pragma unroll
        for (int j = 0; j < 16; ++j) {
            int idx = q * 16 + j;
            float wi = __shfl(w, idx);
            int   si = __shfl(s, idx);
            if (idx < m) acc += wi * bf2f(feat2b[si * 16 + f]);
        }
    }

    for (int off = 32; off > 0; off >>= 1) den += __shfl_down(den, off);
    den = __shfl(den, 0);

    acc += __shfl_down(acc, 32);
    acc += __shfl_down(acc, 16);

    if (lane < 16) {
        float scale = den > 0.f ? 1.f / den : 0.f;
        out[nd * 16 + f] = acc * scale + res[nd * 16 + f];
    }
}

// ---------------------------------------------------------------------------
extern "C" void kernel_launch(void* const* d_in, const int* in_sizes, int n_in,
                              void* d_out, int out_size, void* d_ws, size_t ws_size,
                              hipStream_t stream) {
    const float* inputs = (const float*)d_in[0];
    const int*   src    = (const int*)d_in[1];
    const int*   dst    = (const int*)d_in[2];
    const float* W0     = (const float*)d_in[3];
    const float* al0    = (const float*)d_in[4];
    const float* ar0    = (const float*)d_in[5];
    const float* W1     = (const float*)d_in[6];
    const float* al1    = (const float*)d_in[7];
    const float* ar1    = (const float*)d_in[8];
    const float* W2     = (const float*)d_in[9];
    const float* al2    = (const float*)d_in[10];
    const float* ar2    = (const float*)d_in[11];
    const float* resW2  = (const float*)d_in[12];
    float* out = (float*)d_out;

    const size_t NF = (size_t)N_NODES * 128;
    float* ws   = (float*)d_ws;
    float* hbuf = ws;                                  // N*128 f32
    float* el   = ws + NF;                             // N*4
    float* er   = el + (size_t)N_NODES * 4;            // N*4
    float* res2 = er + (size_t)N_NODES * 4;            // N*16
    unsigned short* featb  = (unsigned short*)(res2 + (size_t)N_NODES * 16);  // N*128
    unsigned short* feat2b = featb + NF;                                      // N*16
    int* iws = (int*)(feat2b + (size_t)N_NODES * 16);  // 8B-aligned (see layout math)
    uint2* pe        = (uint2*)iws;                    // E uint2
    int* deg         = iws + 2 * N_EDGES;              // N
    int* rowptr      = deg + N_NODES;                  // N
    int* sorted_src  = rowptr + N_NODES;               // E
    int* bcount      = sorted_src + N_EDGES;           // 512
    int* bbase       = bcount + NBUCK;                 // 512
    int* bcursor     = bbase + NBUCK;                  // 512

    dim3 blk(256);
    int gemmGrid = (N_NODES + 63) / 64;
    int pGrid    = (N_EDGES + PCHUNK - 1) / PCHUNK;    // 391
    int bGrid    = (N_NODES + 255) / 256;              // 391
    int aggGrid  = N_NODES / 4;                        // 25000

    // ---------------- CSR build (locality-aware counting sort) -------------
    hipMemsetAsync(bcount, 0, NBUCK * sizeof(int), stream);
    bucket_count_k<<<pGrid, blk, 0, stream>>>(dst, bcount, N_EDGES);
    scan512<<<1, NBUCK, 0, stream>>>(bcount, bbase, bcursor);
    partition_k<<<pGrid, dim3(512), 0, stream>>>(src, dst, bcursor, pe, N_EDGES);
    bucket_finalize<<<bGrid, blk, 0, stream>>>(pe, bbase, rowptr, deg, sorted_src, N_EDGES);

    // ---------------- layer 0 ----------------
    gemm128_fused<<<gemmGrid, blk, 0, stream>>>(inputs, W0, al0, ar0, featb, el, er, N_NODES);
    gat_agg128<<<aggGrid, blk, 0, stream>>>(rowptr, deg, sorted_src, el, er, featb,
                                            nullptr, hbuf);

    // ---------------- layer 1 ----------------
    gemm128_fused<<<gemmGrid, blk, 0, stream>>>(hbuf, W1, al1, ar1, featb, el, er, N_NODES);
    gat_agg128<<<aggGrid, blk, 0, stream>>>(rowptr, deg, sorted_src, el, er, featb,
                                            hbuf, hbuf);

    // ---------------- layer 2 ----------------
    gemm16_dual<<<gemmGrid, blk, 0, stream>>>(hbuf, W2, resW2, al2, ar2, feat2b, res2,
                                              el, er, N_NODES);
    gat_agg16<<<aggGrid, blk, 0, stream>>>(rowptr, deg, sorted_src, el, er, feat2b,
                                           res2, out, N_NODES);
}

// Round 6
// 548.326 us; speedup vs baseline: 1.6177x; 1.6177x over previous
//
#include <hip/hip_runtime.h>

#define N_NODES 100000
#define N_EDGES 1600000
#define IN_F    128
#define NEG_SLOPE 0.2f
#define NBUCK   512                 // scan width; active buckets = 391
#define PCHUNK  4096                // edges per partition block

__device__ __forceinline__ float bf2f(unsigned short u) {
    return __uint_as_float(((unsigned int)u) << 16);
}

// f32 -> bf16 round-to-nearest-even
__device__ __forceinline__ unsigned short f2bf(float f) {
    unsigned int u = __float_as_uint(f);
    u += 0x7FFFu + ((u >> 16) & 1u);
    return (unsigned short)(u >> 16);
}

// ---------------------------------------------------------------------------
// Fused GEMM hidden layers: featb(bf16) = A @ W (128x128), el/er in epilogue.
// Scalar-k loop (round-3 body): VGPR ~64, no spills; 2 rows/wave LDS reads
// (2-way broadcast = free on gfx950).
// ---------------------------------------------------------------------------
__global__ __launch_bounds__(256) void gemm128_fused(const float* __restrict__ A,
                                                     const float* __restrict__ W,
                                                     const float* __restrict__ al,
                                                     const float* __restrict__ ar,
                                                     unsigned short* __restrict__ featb,
                                                     float* __restrict__ el,
                                                     float* __restrict__ er,
                                                     int nrows) {
    __shared__ float sH[64][IN_F];
    const int t    = threadIdx.x;
    const int row0 = blockIdx.x * 64;

#pragma unroll
    for (int i = 0; i < 8; ++i) {
        int e4 = i * 256 + t;
        int r  = (e4 * 4) >> 7;
        int c  = (e4 * 4) & 127;
        float4 v = make_float4(0.f, 0.f, 0.f, 0.f);
        int gr = row0 + r;
        if (gr < nrows) v = *(const float4*)(A + (size_t)gr * IN_F + c);
        *(float4*)(&sH[r][c]) = v;
    }
    __syncthreads();

    const int tx  = t & 31;
    const int ty  = t >> 5;
    const int col = tx * 4;

    float4 acc[8];
#pragma unroll
    for (int i = 0; i < 8; ++i) acc[i] = make_float4(0.f, 0.f, 0.f, 0.f);

    for (int k = 0; k < IN_F; ++k) {
        float4 b = *(const float4*)(W + k * 128 + col);
#pragma unroll
        for (int i = 0; i < 8; ++i) {
            float a = sH[ty * 8 + i][k];
            acc[i].x += a * b.x;
            acc[i].y += a * b.y;
            acc[i].z += a * b.z;
            acc[i].w += a * b.w;
        }
    }

    const float4 alv = *(const float4*)(al + col);
    const float4 arv = *(const float4*)(ar + col);
    const int h = tx >> 3;

#pragma unroll
    for (int i = 0; i < 8; ++i) {
        int r = row0 + ty * 8 + i;
        float4 a = acc[i];
        if (r < nrows) {
            ushort4 u;
            u.x = f2bf(a.x); u.y = f2bf(a.y); u.z = f2bf(a.z); u.w = f2bf(a.w);
            *(ushort4*)(featb + (size_t)r * 128 + col) = u;
        }
        float pel = a.x * alv.x + a.y * alv.y + a.z * alv.z + a.w * alv.w;
        float per = a.x * arv.x + a.y * arv.y + a.z * arv.z + a.w * arv.w;
        pel += __shfl_down(pel, 4); per += __shfl_down(per, 4);
        pel += __shfl_down(pel, 2); per += __shfl_down(per, 2);
        pel += __shfl_down(pel, 1); per += __shfl_down(per, 1);
        if ((tx & 7) == 0 && r < nrows) {
            el[r * 4 + h] = pel;
            er[r * 4 + h] = per;
        }
    }
}

// ---------------------------------------------------------------------------
// Dual GEMM layer 2: feat2b(bf16) = A @ W2, res2(f32) = A @ resW2, el/er fused.
// Scalar-k loop; sH padded +4 floats so the 8 distinct rows per wave hit
// distinct banks (bank = (4r+k)%32) instead of 8-way conflicting.
// ---------------------------------------------------------------------------
__global__ __launch_bounds__(256) void gemm16_dual(const float* __restrict__ A,
                                                   const float* __restrict__ W2,
                                                   const float* __restrict__ resW2,
                                                   const float* __restrict__ al,
                                                   const float* __restrict__ ar,
                                                   unsigned short* __restrict__ feat2b,
                                                   float* __restrict__ res2,
                                                   float* __restrict__ el,
                                                   float* __restrict__ er,
                                                   int nrows) {
    __shared__ float sH[64][IN_F + 4];
    const int t    = threadIdx.x;
    const int row0 = blockIdx.x * 64;

#pragma unroll
    for (int i = 0; i < 8; ++i) {
        int e4 = i * 256 + t;
        int r  = (e4 * 4) >> 7;
        int c  = (e4 * 4) & 127;
        float4 v = make_float4(0.f, 0.f, 0.f, 0.f);
        int gr = row0 + r;
        if (gr < nrows) v = *(const float4*)(A + (size_t)gr * IN_F + c);
        *(float4*)(&sH[r][c]) = v;
    }
    __syncthreads();

    const int tx   = t & 7;
    const int ty   = t >> 3;
    const bool isW = tx < 4;
    const int col  = (isW ? tx : tx - 4) * 4;
    const float* Wp = isW ? W2 : resW2;

    float4 acc[2];
    acc[0] = make_float4(0.f, 0.f, 0.f, 0.f);
    acc[1] = make_float4(0.f, 0.f, 0.f, 0.f);

    for (int k = 0; k < IN_F; ++k) {
        float4 b = *(const float4*)(Wp + k * 16 + col);
#pragma unroll
        for (int i = 0; i < 2; ++i) {
            float a = sH[ty * 2 + i][k];
            acc[i].x += a * b.x;
            acc[i].y += a * b.y;
            acc[i].z += a * b.z;
            acc[i].w += a * b.w;
        }
    }

    const float4 alv = isW ? *(const float4*)(al + col) : make_float4(0, 0, 0, 0);
    const float4 arv = isW ? *(const float4*)(ar + col) : make_float4(0, 0, 0, 0);

#pragma unroll
    for (int i = 0; i < 2; ++i) {
        int r = row0 + ty * 2 + i;
        float4 a = acc[i];
        if (isW) {
            if (r < nrows) {
                ushort4 u;
                u.x = f2bf(a.x); u.y = f2bf(a.y); u.z = f2bf(a.z); u.w = f2bf(a.w);
                *(ushort4*)(feat2b + (size_t)r * 16 + col) = u;
            }
            float pel = a.x * alv.x + a.y * alv.y + a.z * alv.z + a.w * alv.w;
            float per = a.x * arv.x + a.y * arv.y + a.z * arv.z + a.w * arv.w;
            pel += __shfl_down(pel, 2); per += __shfl_down(per, 2);
            pel += __shfl_down(pel, 1); per += __shfl_down(per, 1);
            if (tx == 0 && r < nrows) { el[r] = pel; er[r] = per; }
        } else if (r < nrows) {
            *(float4*)(res2 + (size_t)r * 16 + col) = a;
        }
    }
}

// ---------------------------------------------------------------------------
// CSR build, locality-aware. Bucket = dst>>8 (256-node windows, 391 active).
// ---------------------------------------------------------------------------
__global__ __launch_bounds__(256) void bucket_count_k(const int* __restrict__ dst,
                                                      int* __restrict__ bcount, int nE) {
    __shared__ int hist[NBUCK];
    const int t = threadIdx.x;
    hist[t] = 0; hist[t + 256] = 0;
    __syncthreads();
    const int start = blockIdx.x * PCHUNK;
#pragma unroll
    for (int j = 0; j < PCHUNK / 256; ++j) {
        int e = start + j * 256 + t;
        if (e < nE) atomicAdd(&hist[dst[e] >> 8], 1);
    }
    __syncthreads();
    if (hist[t])       atomicAdd(&bcount[t],       hist[t]);
    if (hist[t + 256]) atomicAdd(&bcount[t + 256], hist[t + 256]);
}

// exclusive scan of bucket counts -> base; cursor initialized to base
__global__ __launch_bounds__(NBUCK) void scan512(const int* __restrict__ bcount,
                                                 int* __restrict__ bbase,
                                                 int* __restrict__ bcursor) {
    __shared__ int s[NBUCK];
    const int t = threadIdx.x;
    int v = bcount[t];
    s[t] = v;
    __syncthreads();
#pragma unroll
    for (int off = 1; off < NBUCK; off <<= 1) {
        int x = (t >= off) ? s[t - off] : 0;
        __syncthreads();
        s[t] += x;
        __syncthreads();
    }
    int excl = s[t] - v;
    bbase[t]   = excl;
    bcursor[t] = excl;
}

// Counting-sort PCHUNK edges by bucket in LDS, flush coalesced runs.
__global__ __launch_bounds__(512) void partition_k(const int* __restrict__ src,
                                                   const int* __restrict__ dst,
                                                   int* __restrict__ bcursor,
                                                   uint2* __restrict__ pe, int nE) {
    __shared__ int   hist[NBUCK];
    __shared__ int   lstart[NBUCK];
    __shared__ int   gbase[NBUCK];
    __shared__ int   curB[NBUCK];
    __shared__ uint2 reorder[PCHUNK];

    const int t = threadIdx.x;
    const int start = blockIdx.x * PCHUNK;
    const int m = min(PCHUNK, nE - start);

    hist[t] = 0;
    __syncthreads();

#pragma unroll
    for (int j = 0; j < PCHUNK / 512; ++j) {
        int e = start + j * 512 + t;
        if (e < nE) atomicAdd(&hist[dst[e] >> 8], 1);
    }
    __syncthreads();
    const int cnt = hist[t];

    __shared__ int s[NBUCK];
    s[t] = cnt;
    __syncthreads();
#pragma unroll
    for (int off = 1; off < NBUCK; off <<= 1) {
        int x = (t >= off) ? s[t - off] : 0;
        __syncthreads();
        s[t] += x;
        __syncthreads();
    }
    lstart[t] = s[t] - cnt;
    curB[t]   = s[t] - cnt;
    gbase[t] = cnt ? atomicAdd(&bcursor[t], cnt) : 0;
    __syncthreads();

#pragma unroll
    for (int j = 0; j < PCHUNK / 512; ++j) {
        int e = start + j * 512 + t;
        if (e < nE) {
            int d = dst[e];
            int pos = atomicAdd(&curB[d >> 8], 1);
            reorder[pos] = make_uint2((unsigned)src[e], (unsigned)d);
        }
    }
    __syncthreads();

    for (int i = t; i < m; i += 512) {
        uint2 ed = reorder[i];
        int b = (int)(ed.y >> 8);
        pe[gbase[b] + (i - lstart[b])] = ed;
    }
}

// One block per bucket: local degree histogram + scan -> rowptr/deg/sorted_src
__global__ __launch_bounds__(256) void bucket_finalize(const uint2* __restrict__ pe,
                                                       const int* __restrict__ bbase,
                                                       int* __restrict__ rowptr,
                                                       int* __restrict__ deg,
                                                       int* __restrict__ sorted_src,
                                                       int nE) {
    __shared__ int deg_l[256];
    __shared__ int s[256];
    __shared__ int cur[256];

    const int b  = blockIdx.x;
    const int t  = threadIdx.x;
    const int base = bbase[b];
    const int endE = (b + 1 < NBUCK) ? bbase[b + 1] : nE;
    const int cnt  = endE - base;
    const int n    = b * 256 + t;

    deg_l[t] = 0;
    __syncthreads();
    for (int i = t; i < cnt; i += 256)
        atomicAdd(&deg_l[pe[base + i].y & 255u], 1);
    __syncthreads();

    const int dv = deg_l[t];
    s[t] = dv;
    __syncthreads();
#pragma unroll
    for (int off = 1; off < 256; off <<= 1) {
        int x = (t >= off) ? s[t - off] : 0;
        __syncthreads();
        s[t] += x;
        __syncthreads();
    }
    const int off_l = s[t] - dv;
    if (n < N_NODES) {
        rowptr[n] = base + off_l;
        deg[n]    = dv;
    }
    cur[t] = off_l;
    __syncthreads();

    for (int i = t; i < cnt; i += 256) {
        uint2 ed = pe[base + i];
        int pos = atomicAdd(&cur[ed.y & 255u], 1);
        sorted_src[base + pos] = (int)ed.x;
    }
}

// ---------------------------------------------------------------------------
// Pull aggregation, H=4, D=32 (128 feats), bf16 gathers, wave per node.
// ---------------------------------------------------------------------------
__global__ __launch_bounds__(256) void gat_agg128(const int* __restrict__ rowptr,
                                                  const int* __restrict__ deg,
                                                  const int* __restrict__ sorted_src,
                                                  const float* __restrict__ el,
                                                  const float* __restrict__ er,
                                                  const unsigned short* __restrict__ featb,
                                                  const float* __restrict__ res,
                                                  float* __restrict__ out) {
    __shared__ int   sS[4][64];
    __shared__ float sW[4][64][4];

    const int wv   = threadIdx.x >> 6;
    const int lane = threadIdx.x & 63;
    const int nd   = blockIdx.x * 4 + wv;

    const int dg = deg[nd];
    const int r0 = rowptr[nd];
    const int h  = lane >> 4;
    const float4 er4 = *(const float4*)(er + nd * 4);

    float den = 0.f;
    float ax = 0.f, ay = 0.f;

    for (int base = 0; base < dg; base += 64) {
        int m = dg - base; if (m > 64) m = 64;
        if (lane < m) {
            int s = sorted_src[r0 + base + lane];
            sS[wv][lane] = s;
            float4 e4 = *(const float4*)(el + s * 4);
            float4 w;
            float v;
            v = e4.x + er4.x; v = v > 0.f ? v : NEG_SLOPE * v; w.x = __expf(v);
            v = e4.y + er4.y; v = v > 0.f ? v : NEG_SLOPE * v; w.y = __expf(v);
            v = e4.z + er4.z; v = v > 0.f ? v : NEG_SLOPE * v; w.z = __expf(v);
            v = e4.w + er4.w; v = v > 0.f ? v : NEG_SLOPE * v; w.w = __expf(v);
            *(float4*)(&sW[wv][lane][0]) = w;
        }
        for (int i = 0; i < m; ++i) {
            int s   = sS[wv][i];
            float w = sW[wv][i][h];
            den += w;
            ushort2 u = *(const ushort2*)(featb + (size_t)s * 128 + lane * 2);
            ax += w * bf2f(u.x);
            ay += w * bf2f(u.y);
        }
    }

    float scale = den > 0.f ? 1.f / den : 0.f;
    float ox = ax * scale, oy = ay * scale;
    size_t o0 = (size_t)nd * 128 + lane * 2;
    if (res) { ox += res[o0]; oy += res[o0 + 1]; }
    ox = fmaxf(ox, 0.f);
    oy = fmaxf(oy, 0.f);
    *(float2*)(out + o0) = make_float2(ox, oy);
}

// ---------------------------------------------------------------------------
// Pull aggregation, H=1, C=16, bf16 gathers, wave per node, shuffle staging.
// ---------------------------------------------------------------------------
__global__ __launch_bounds__(256) void gat_agg16(const int* __restrict__ rowptr,
                                                 const int* __restrict__ deg,
                                                 const int* __restrict__ sorted_src,
                                                 const float* __restrict__ el,
                                                 const float* __restrict__ er,
                                                 const unsigned short* __restrict__ feat2b,
                                                 const float* __restrict__ res,
                                                 float* __restrict__ out, int n) {
    const int t    = threadIdx.x;
    const int nd   = blockIdx.x * 4 + (t >> 6);
    const int lane = t & 63;
    if (nd >= n) return;

    const int f = lane & 15;
    const int q = lane >> 4;
    const int dg = deg[nd];
    const int r0 = rowptr[nd];
    const float erd = er[nd];

    float acc = 0.f, den = 0.f;

    for (int base = 0; base < dg; base += 64) {
        int m = dg - base; if (m > 64) m = 64;
        int s = 0; float w = 0.f;
        if (lane < m) {
            s = sorted_src[r0 + base + lane];
            float v = el[s] + erd;
            v = v > 0.f ? v : NEG_SLOPE * v;
            w = __expf(v);
        }
        den += w;
#pragma unroll
        for (int j = 0; j < 16; ++j) {
            int idx = q * 16 + j;
            float wi = __shfl(w, idx);
            int   si = __shfl(s, idx);
            if (idx < m) acc += wi * bf2f(feat2b[si * 16 + f]);
        }
    }

    for (int off = 32; off > 0; off >>= 1) den += __shfl_down(den, off);
    den = __shfl(den, 0);

    acc += __shfl_down(acc, 32);
    acc += __shfl_down(acc, 16);

    if (lane < 16) {
        float scale = den > 0.f ? 1.f / den : 0.f;
        out[nd * 16 + f] = acc * scale + res[nd * 16 + f];
    }
}

// ---------------------------------------------------------------------------
extern "C" void kernel_launch(void* const* d_in, const int* in_sizes, int n_in,
                              void* d_out, int out_size, void* d_ws, size_t ws_size,
                              hipStream_t stream) {
    const float* inputs = (const float*)d_in[0];
    const int*   src    = (const int*)d_in[1];
    const int*   dst    = (const int*)d_in[2];
    const float* W0     = (const float*)d_in[3];
    const float* al0    = (const float*)d_in[4];
    const float* ar0    = (const float*)d_in[5];
    const float* W1     = (const float*)d_in[6];
    const float* al1    = (const float*)d_in[7];
    const float* ar1    = (const float*)d_in[8];
    const float* W2     = (const float*)d_in[9];
    const float* al2    = (const float*)d_in[10];
    const float* ar2    = (const float*)d_in[11];
    const float* resW2  = (const float*)d_in[12];
    float* out = (float*)d_out;

    const size_t NF = (size_t)N_NODES * 128;
    float* ws   = (float*)d_ws;
    float* hbuf = ws;                                  // N*128 f32
    float* el   = ws + NF;                             // N*4
    float* er   = el + (size_t)N_NODES * 4;            // N*4
    float* res2 = er + (size_t)N_NODES * 4;            // N*16
    unsigned short* featb  = (unsigned short*)(res2 + (size_t)N_NODES * 16);  // N*128
    unsigned short* feat2b = featb + NF;                                      // N*16
    int* iws = (int*)(feat2b + (size_t)N_NODES * 16);
    uint2* pe        = (uint2*)iws;                    // E uint2
    int* deg         = iws + 2 * N_EDGES;              // N
    int* rowptr      = deg + N_NODES;                  // N
    int* sorted_src  = rowptr + N_NODES;               // E
    int* bcount      = sorted_src + N_EDGES;           // 512
    int* bbase       = bcount + NBUCK;                 // 512
    int* bcursor     = bbase + NBUCK;                  // 512

    dim3 blk(256);
    int gemmGrid = (N_NODES + 63) / 64;
    int pGrid    = (N_EDGES + PCHUNK - 1) / PCHUNK;    // 391
    int bGrid    = (N_NODES + 255) / 256;              // 391
    int aggGrid  = N_NODES / 4;                        // 25000

    // ---------------- CSR build (locality-aware counting sort) -------------
    hipMemsetAsync(bcount, 0, NBUCK * sizeof(int), stream);
    bucket_count_k<<<pGrid, blk, 0, stream>>>(dst, bcount, N_EDGES);
    scan512<<<1, NBUCK, 0, stream>>>(bcount, bbase, bcursor);
    partition_k<<<pGrid, dim3(512), 0, stream>>>(src, dst, bcursor, pe, N_EDGES);
    bucket_finalize<<<bGrid, blk, 0, stream>>>(pe, bbase, rowptr, deg, sorted_src, N_EDGES);

    // ---------------- layer 0 ----------------
    gemm128_fused<<<gemmGrid, blk, 0, stream>>>(inputs, W0, al0, ar0, featb, el, er, N_NODES);
    gat_agg128<<<aggGrid, blk, 0, stream>>>(rowptr, deg, sorted_src, el, er, featb,
                                            nullptr, hbuf);

    // ---------------- layer 1 ----------------
    gemm128_fused<<<gemmGrid, blk, 0, stream>>>(hbuf, W1, al1, ar1, featb, el, er, N_NODES);
    gat_agg128<<<aggGrid, blk, 0, stream>>>(rowptr, deg, sorted_src, el, er, featb,
                                            hbuf, hbuf);

    // ---------------- layer 2 ----------------
    gemm16_dual<<<gemmGrid, blk, 0, stream>>>(hbuf, W2, resW2, al2, ar2, feat2b, res2,
                                              el, er, N_NODES);
    gat_agg16<<<aggGrid, blk, 0, stream>>>(rowptr, deg, sorted_src, el, er, feat2b,
                                           res2, out, N_NODES);
}

// Round 7
// 495.960 us; speedup vs baseline: 1.7886x; 1.1056x over previous
//
#include <hip/hip_runtime.h>

#define N_NODES 100000
#define N_EDGES 1600000
#define IN_F    128
#define NEG_SLOPE 0.2f
#define NBUCK   512                 // scan width; active buckets = 391
#define PCHUNK  4096                // edges per partition block

__device__ __forceinline__ float bf2f(unsigned short u) {
    return __uint_as_float(((unsigned int)u) << 16);
}

// f32 -> bf16 round-to-nearest-even
__device__ __forceinline__ unsigned short f2bf(float f) {
    unsigned int u = __float_as_uint(f);
    u += 0x7FFFu + ((u >> 16) & 1u);
    return (unsigned short)(u >> 16);
}

// ---------------------------------------------------------------------------
// Fused GEMM hidden layers: featb(bf16) = A @ W (128x128), el/er in epilogue.
// Scalar-k loop: VGPR ~64, no spills (x4 unroll spilled at 256 VGPR, round 5).
// ---------------------------------------------------------------------------
__global__ __launch_bounds__(256) void gemm128_fused(const float* __restrict__ A,
                                                     const float* __restrict__ W,
                                                     const float* __restrict__ al,
                                                     const float* __restrict__ ar,
                                                     unsigned short* __restrict__ featb,
                                                     float* __restrict__ el,
                                                     float* __restrict__ er,
                                                     int nrows) {
    __shared__ float sH[64][IN_F];
    const int t    = threadIdx.x;
    const int row0 = blockIdx.x * 64;

#pragma unroll
    for (int i = 0; i < 8; ++i) {
        int e4 = i * 256 + t;
        int r  = (e4 * 4) >> 7;
        int c  = (e4 * 4) & 127;
        float4 v = make_float4(0.f, 0.f, 0.f, 0.f);
        int gr = row0 + r;
        if (gr < nrows) v = *(const float4*)(A + (size_t)gr * IN_F + c);
        *(float4*)(&sH[r][c]) = v;
    }
    __syncthreads();

    const int tx  = t & 31;
    const int ty  = t >> 5;
    const int col = tx * 4;

    float4 acc[8];
#pragma unroll
    for (int i = 0; i < 8; ++i) acc[i] = make_float4(0.f, 0.f, 0.f, 0.f);

    for (int k = 0; k < IN_F; ++k) {
        float4 b = *(const float4*)(W + k * 128 + col);
#pragma unroll
        for (int i = 0; i < 8; ++i) {
            float a = sH[ty * 8 + i][k];
            acc[i].x += a * b.x;
            acc[i].y += a * b.y;
            acc[i].z += a * b.z;
            acc[i].w += a * b.w;
        }
    }

    const float4 alv = *(const float4*)(al + col);
    const float4 arv = *(const float4*)(ar + col);
    const int h = tx >> 3;

#pragma unroll
    for (int i = 0; i < 8; ++i) {
        int r = row0 + ty * 8 + i;
        float4 a = acc[i];
        if (r < nrows) {
            ushort4 u;
            u.x = f2bf(a.x); u.y = f2bf(a.y); u.z = f2bf(a.z); u.w = f2bf(a.w);
            *(ushort4*)(featb + (size_t)r * 128 + col) = u;
        }
        float pel = a.x * alv.x + a.y * alv.y + a.z * alv.z + a.w * alv.w;
        float per = a.x * arv.x + a.y * arv.y + a.z * arv.z + a.w * arv.w;
        pel += __shfl_down(pel, 4); per += __shfl_down(per, 4);
        pel += __shfl_down(pel, 2); per += __shfl_down(per, 2);
        pel += __shfl_down(pel, 1); per += __shfl_down(per, 1);
        if ((tx & 7) == 0 && r < nrows) {
            el[r * 4 + h] = pel;
            er[r * 4 + h] = per;
        }
    }
}

// ---------------------------------------------------------------------------
// Dual GEMM layer 2: feat2b(bf16) = A @ W2, res2(f32) = A @ resW2, el/er fused.
// sH padded +4 so 8 distinct rows/wave hit distinct banks.
// ---------------------------------------------------------------------------
__global__ __launch_bounds__(256) void gemm16_dual(const float* __restrict__ A,
                                                   const float* __restrict__ W2,
                                                   const float* __restrict__ resW2,
                                                   const float* __restrict__ al,
                                                   const float* __restrict__ ar,
                                                   unsigned short* __restrict__ feat2b,
                                                   float* __restrict__ res2,
                                                   float* __restrict__ el,
                                                   float* __restrict__ er,
                                                   int nrows) {
    __shared__ float sH[64][IN_F + 4];
    const int t    = threadIdx.x;
    const int row0 = blockIdx.x * 64;

#pragma unroll
    for (int i = 0; i < 8; ++i) {
        int e4 = i * 256 + t;
        int r  = (e4 * 4) >> 7;
        int c  = (e4 * 4) & 127;
        float4 v = make_float4(0.f, 0.f, 0.f, 0.f);
        int gr = row0 + r;
        if (gr < nrows) v = *(const float4*)(A + (size_t)gr * IN_F + c);
        *(float4*)(&sH[r][c]) = v;
    }
    __syncthreads();

    const int tx   = t & 7;
    const int ty   = t >> 3;
    const bool isW = tx < 4;
    const int col  = (isW ? tx : tx - 4) * 4;
    const float* Wp = isW ? W2 : resW2;

    float4 acc[2];
    acc[0] = make_float4(0.f, 0.f, 0.f, 0.f);
    acc[1] = make_float4(0.f, 0.f, 0.f, 0.f);

    for (int k = 0; k < IN_F; ++k) {
        float4 b = *(const float4*)(Wp + k * 16 + col);
#pragma unroll
        for (int i = 0; i < 2; ++i) {
            float a = sH[ty * 2 + i][k];
            acc[i].x += a * b.x;
            acc[i].y += a * b.y;
            acc[i].z += a * b.z;
            acc[i].w += a * b.w;
        }
    }

    const float4 alv = isW ? *(const float4*)(al + col) : make_float4(0, 0, 0, 0);
    const float4 arv = isW ? *(const float4*)(ar + col) : make_float4(0, 0, 0, 0);

#pragma unroll
    for (int i = 0; i < 2; ++i) {
        int r = row0 + ty * 2 + i;
        float4 a = acc[i];
        if (isW) {
            if (r < nrows) {
                ushort4 u;
                u.x = f2bf(a.x); u.y = f2bf(a.y); u.z = f2bf(a.z); u.w = f2bf(a.w);
                *(ushort4*)(feat2b + (size_t)r * 16 + col) = u;
            }
            float pel = a.x * alv.x + a.y * alv.y + a.z * alv.z + a.w * alv.w;
            float per = a.x * arv.x + a.y * arv.y + a.z * arv.z + a.w * arv.w;
            pel += __shfl_down(pel, 2); per += __shfl_down(per, 2);
            pel += __shfl_down(pel, 1); per += __shfl_down(per, 1);
            if (tx == 0 && r < nrows) { el[r] = pel; er[r] = per; }
        } else if (r < nrows) {
            *(float4*)(res2 + (size_t)r * 16 + col) = a;
        }
    }
}

// ---------------------------------------------------------------------------
// CSR build, locality-aware. Bucket = dst>>8 (256-node windows, 391 active).
// ---------------------------------------------------------------------------
__global__ __launch_bounds__(256) void bucket_count_k(const int* __restrict__ dst,
                                                      int* __restrict__ bcount, int nE) {
    __shared__ int hist[NBUCK];
    const int t = threadIdx.x;
    hist[t] = 0; hist[t + 256] = 0;
    __syncthreads();
    const int start = blockIdx.x * PCHUNK;
#pragma unroll
    for (int j = 0; j < PCHUNK / 256; ++j) {
        int e = start + j * 256 + t;
        if (e < nE) atomicAdd(&hist[dst[e] >> 8], 1);
    }
    __syncthreads();
    if (hist[t])       atomicAdd(&bcount[t],       hist[t]);
    if (hist[t + 256]) atomicAdd(&bcount[t + 256], hist[t + 256]);
}

__global__ __launch_bounds__(NBUCK) void scan512(const int* __restrict__ bcount,
                                                 int* __restrict__ bbase,
                                                 int* __restrict__ bcursor) {
    __shared__ int s[NBUCK];
    const int t = threadIdx.x;
    int v = bcount[t];
    s[t] = v;
    __syncthreads();
#pragma unroll
    for (int off = 1; off < NBUCK; off <<= 1) {
        int x = (t >= off) ? s[t - off] : 0;
        __syncthreads();
        s[t] += x;
        __syncthreads();
    }
    int excl = s[t] - v;
    bbase[t]   = excl;
    bcursor[t] = excl;
}

__global__ __launch_bounds__(512) void partition_k(const int* __restrict__ src,
                                                   const int* __restrict__ dst,
                                                   int* __restrict__ bcursor,
                                                   uint2* __restrict__ pe, int nE) {
    __shared__ int   hist[NBUCK];
    __shared__ int   lstart[NBUCK];
    __shared__ int   gbase[NBUCK];
    __shared__ int   curB[NBUCK];
    __shared__ uint2 reorder[PCHUNK];

    const int t = threadIdx.x;
    const int start = blockIdx.x * PCHUNK;
    const int m = min(PCHUNK, nE - start);

    hist[t] = 0;
    __syncthreads();

#pragma unroll
    for (int j = 0; j < PCHUNK / 512; ++j) {
        int e = start + j * 512 + t;
        if (e < nE) atomicAdd(&hist[dst[e] >> 8], 1);
    }
    __syncthreads();
    const int cnt = hist[t];

    __shared__ int s[NBUCK];
    s[t] = cnt;
    __syncthreads();
#pragma unroll
    for (int off = 1; off < NBUCK; off <<= 1) {
        int x = (t >= off) ? s[t - off] : 0;
        __syncthreads();
        s[t] += x;
        __syncthreads();
    }
    lstart[t] = s[t] - cnt;
    curB[t]   = s[t] - cnt;
    gbase[t] = cnt ? atomicAdd(&bcursor[t], cnt) : 0;
    __syncthreads();

#pragma unroll
    for (int j = 0; j < PCHUNK / 512; ++j) {
        int e = start + j * 512 + t;
        if (e < nE) {
            int d = dst[e];
            int pos = atomicAdd(&curB[d >> 8], 1);
            reorder[pos] = make_uint2((unsigned)src[e], (unsigned)d);
        }
    }
    __syncthreads();

    for (int i = t; i < m; i += 512) {
        uint2 ed = reorder[i];
        int b = (int)(ed.y >> 8);
        pe[gbase[b] + (i - lstart[b])] = ed;
    }
}

__global__ __launch_bounds__(256) void bucket_finalize(const uint2* __restrict__ pe,
                                                       const int* __restrict__ bbase,
                                                       int* __restrict__ rowptr,
                                                       int* __restrict__ deg,
                                                       int* __restrict__ sorted_src,
                                                       int nE) {
    __shared__ int deg_l[256];
    __shared__ int s[256];
    __shared__ int cur[256];

    const int b  = blockIdx.x;
    const int t  = threadIdx.x;
    const int base = bbase[b];
    const int endE = (b + 1 < NBUCK) ? bbase[b + 1] : nE;
    const int cnt  = endE - base;
    const int n    = b * 256 + t;

    deg_l[t] = 0;
    __syncthreads();
    for (int i = t; i < cnt; i += 256)
        atomicAdd(&deg_l[pe[base + i].y & 255u], 1);
    __syncthreads();

    const int dv = deg_l[t];
    s[t] = dv;
    __syncthreads();
#pragma unroll
    for (int off = 1; off < 256; off <<= 1) {
        int x = (t >= off) ? s[t - off] : 0;
        __syncthreads();
        s[t] += x;
        __syncthreads();
    }
    const int off_l = s[t] - dv;
    if (n < N_NODES) {
        rowptr[n] = base + off_l;
        deg[n]    = dv;
    }
    cur[t] = off_l;
    __syncthreads();

    for (int i = t; i < cnt; i += 256) {
        uint2 ed = pe[base + i];
        int pos = atomicAdd(&cur[ed.y & 255u], 1);
        sorted_src[base + pos] = (int)ed.x;
    }
}

// ---------------------------------------------------------------------------
// Pull aggregation, H=4, D=32 (128 feats), bf16 gathers, wave per node.
// ---------------------------------------------------------------------------
__global__ __launch_bounds__(256) void gat_agg128(const int* __restrict__ rowptr,
                                                  const int* __restrict__ deg,
                                                  const int* __restrict__ sorted_src,
                                                  const float* __restrict__ el,
                                                  const float* __restrict__ er,
                                                  const unsigned short* __restrict__ featb,
                                                  const float* __restrict__ res,
                                                  float* __restrict__ out) {
    __shared__ int   sS[4][64];
    __shared__ float sW[4][64][4];

    const int wv   = threadIdx.x >> 6;
    const int lane = threadIdx.x & 63;
    const int nd   = blockIdx.x * 4 + wv;

    const int dg = deg[nd];
    const int r0 = rowptr[nd];
    const int h  = lane >> 4;
    const float4 er4 = *(const float4*)(er + nd * 4);

    float den = 0.f;
    float ax = 0.f, ay = 0.f;

    for (int base = 0; base < dg; base += 64) {
        int m = dg - base; if (m > 64) m = 64;
        if (lane < m) {
            int s = sorted_src[r0 + base + lane];
            sS[wv][lane] = s;
            float4 e4 = *(const float4*)(el + s * 4);
            float4 w;
            float v;
            v = e4.x + er4.x; v = v > 0.f ? v : NEG_SLOPE * v; w.x = __expf(v);
            v = e4.y + er4.y; v = v > 0.f ? v : NEG_SLOPE * v; w.y = __expf(v);
            v = e4.z + er4.z; v = v > 0.f ? v : NEG_SLOPE * v; w.z = __expf(v);
            v = e4.w + er4.w; v = v > 0.f ? v : NEG_SLOPE * v; w.w = __expf(v);
            *(float4*)(&sW[wv][lane][0]) = w;
        }
        for (int i = 0; i < m; ++i) {
            int s   = sS[wv][i];
            float w = sW[wv][i][h];
            den += w;
            ushort2 u = *(const ushort2*)(featb + (size_t)s * 128 + lane * 2);
            ax += w * bf2f(u.x);
            ay += w * bf2f(u.y);
        }
    }

    float scale = den > 0.f ? 1.f / den : 0.f;
    float ox = ax * scale, oy = ay * scale;
    size_t o0 = (size_t)nd * 128 + lane * 2;
    if (res) { ox += res[o0]; oy += res[o0 + 1]; }
    ox = fmaxf(ox, 0.f);
    oy = fmaxf(oy, 0.f);
    *(float2*)(out + o0) = make_float2(ox, oy);
}

// ---------------------------------------------------------------------------
// Pull aggregation, H=1, C=16: wave per node, LDS staging, 8 edge-groups of
// 8 lanes; lane owns a feature PAIR (ushort2). All 64 lanes active, no
// shuffles in the loop; 3-step cross-group reduction at the end.
// ---------------------------------------------------------------------------
__global__ __launch_bounds__(256) void gat_agg16(const int* __restrict__ rowptr,
                                                 const int* __restrict__ deg,
                                                 const int* __restrict__ sorted_src,
                                                 const float* __restrict__ el,
                                                 const float* __restrict__ er,
                                                 const unsigned short* __restrict__ feat2b,
                                                 const float* __restrict__ res,
                                                 float* __restrict__ out) {
    __shared__ int   sS[4][64];
    __shared__ float sW[4][64];

    const int wv   = threadIdx.x >> 6;
    const int lane = threadIdx.x & 63;
    const int nd   = blockIdx.x * 4 + wv;
    const int g    = lane >> 3;          // edge group 0..7
    const int f2   = (lane & 7) * 2;     // feature pair base

    const int dg = deg[nd];
    const int r0 = rowptr[nd];
    const float erd = er[nd];

    float ax = 0.f, ay = 0.f, den = 0.f;

    for (int base = 0; base < dg; base += 64) {
        int m = dg - base; if (m > 64) m = 64;
        if (lane < m) {
            int s = sorted_src[r0 + base + lane];
            sS[wv][lane] = s;
            float v = el[s] + erd;
            v = v > 0.f ? v : NEG_SLOPE * v;
            sW[wv][lane] = __expf(v);
        }
        // wave-synchronous LDS (same wave wrote it)
        for (int i = g; i < m; i += 8) {
            int s   = sS[wv][i];
            float w = sW[wv][i];
            den += w;
            ushort2 u = *(const ushort2*)(feat2b + (size_t)s * 16 + f2);
            ax += w * bf2f(u.x);
            ay += w * bf2f(u.y);
        }
    }

    // reduce across the 8 groups (each lane keeps its feature pair)
    ax += __shfl_down(ax, 32); ay += __shfl_down(ay, 32); den += __shfl_down(den, 32);
    ax += __shfl_down(ax, 16); ay += __shfl_down(ay, 16); den += __shfl_down(den, 16);
    ax += __shfl_down(ax, 8);  ay += __shfl_down(ay, 8);  den += __shfl_down(den, 8);

    if (lane < 8) {
        float scale = den > 0.f ? 1.f / den : 0.f;
        size_t o0 = (size_t)nd * 16 + f2;
        float2 o;
        o.x = ax * scale + res[o0];
        o.y = ay * scale + res[o0 + 1];
        *(float2*)(out + o0) = o;
    }
}

// ---------------------------------------------------------------------------
extern "C" void kernel_launch(void* const* d_in, const int* in_sizes, int n_in,
                              void* d_out, int out_size, void* d_ws, size_t ws_size,
                              hipStream_t stream) {
    const float* inputs = (const float*)d_in[0];
    const int*   src    = (const int*)d_in[1];
    const int*   dst    = (const int*)d_in[2];
    const float* W0     = (const float*)d_in[3];
    const float* al0    = (const float*)d_in[4];
    const float* ar0    = (const float*)d_in[5];
    const float* W1     = (const float*)d_in[6];
    const float* al1    = (const float*)d_in[7];
    const float* ar1    = (const float*)d_in[8];
    const float* W2     = (const float*)d_in[9];
    const float* al2    = (const float*)d_in[10];
    const float* ar2    = (const float*)d_in[11];
    const float* resW2  = (const float*)d_in[12];
    float* out = (float*)d_out;

    const size_t NF = (size_t)N_NODES * 128;
    float* ws   = (float*)d_ws;
    float* hbuf = ws;                                  // N*128 f32
    float* el   = ws + NF;                             // N*4
    float* er   = el + (size_t)N_NODES * 4;            // N*4
    float* res2 = er + (size_t)N_NODES * 4;            // N*16
    unsigned short* featb  = (unsigned short*)(res2 + (size_t)N_NODES * 16);  // N*128
    unsigned short* feat2b = featb + NF;                                      // N*16
    int* iws = (int*)(feat2b + (size_t)N_NODES * 16);
    uint2* pe        = (uint2*)iws;                    // E uint2
    int* deg         = iws + 2 * N_EDGES;              // N
    int* rowptr      = deg + N_NODES;                  // N
    int* sorted_src  = rowptr + N_NODES;               // E
    int* bcount      = sorted_src + N_EDGES;           // 512
    int* bbase       = bcount + NBUCK;                 // 512
    int* bcursor     = bbase + NBUCK;                  // 512

    dim3 blk(256);
    int gemmGrid = (N_NODES + 63) / 64;
    int pGrid    = (N_EDGES + PCHUNK - 1) / PCHUNK;    // 391
    int bGrid    = (N_NODES + 255) / 256;              // 391
    int aggGrid  = N_NODES / 4;                        // 25000

    // ---------------- CSR build (locality-aware counting sort) -------------
    hipMemsetAsync(bcount, 0, NBUCK * sizeof(int), stream);
    bucket_count_k<<<pGrid, blk, 0, stream>>>(dst, bcount, N_EDGES);
    scan512<<<1, NBUCK, 0, stream>>>(bcount, bbase, bcursor);
    partition_k<<<pGrid, dim3(512), 0, stream>>>(src, dst, bcursor, pe, N_EDGES);
    bucket_finalize<<<bGrid, blk, 0, stream>>>(pe, bbase, rowptr, deg, sorted_src, N_EDGES);

    // ---------------- layer 0 ----------------
    gemm128_fused<<<gemmGrid, blk, 0, stream>>>(inputs, W0, al0, ar0, featb, el, er, N_NODES);
    gat_agg128<<<aggGrid, blk, 0, stream>>>(rowptr, deg, sorted_src, el, er, featb,
                                            nullptr, hbuf);

    // ---------------- layer 1 ----------------
    gemm128_fused<<<gemmGrid, blk, 0, stream>>>(hbuf, W1, al1, ar1, featb, el, er, N_NODES);
    gat_agg128<<<aggGrid, blk, 0, stream>>>(rowptr, deg, sorted_src, el, er, featb,
                                            hbuf, hbuf);

    // ---------------- layer 2 ----------------
    gemm16_dual<<<gemmGrid, blk, 0, stream>>>(hbuf, W2, resW2, al2, ar2, feat2b, res2,
                                              el, er, N_NODES);
    gat_agg16<<<aggGrid, blk, 0, stream>>>(rowptr, deg, sorted_src, el, er, feat2b,
                                           res2, out);
}